// Round 13
// baseline (134.659 us; speedup 1.0000x reference)
//
#include <hip/hip_runtime.h>
#include <hip/hip_bf16.h>
#include <cstdint>
#include <cstddef>

typedef __bf16 bf16;
typedef __attribute__((ext_vector_type(4))) float f32x4;
typedef __attribute__((ext_vector_type(16))) float f32x16;
typedef __attribute__((ext_vector_type(8))) __bf16 bf16x8;
typedef __attribute__((ext_vector_type(4))) __bf16 bf16x4;
typedef __attribute__((ext_vector_type(4))) unsigned int u32x4;

#define D_MODEL 1024
#define NHEADS  16
#define DHEAD   64
#define SEQ     2048
#define BATCH   2
#define MROWS   (BATCH*SEQ)   /* 4096 */
#define BHTOT   (BATCH*NHEADS) /* 32 */

// 0.125 (1/sqrt(64)) * log2(e): fold into q so softmax uses exp2
#define QSCALE 0.18033688011112042f
// defer-max threshold in log2 units (HK's THR=8 nats * log2e)
#define DEFER_THR 11.5f

__device__ __forceinline__ void gload16(const bf16* g, bf16* l) {
  __builtin_amdgcn_global_load_lds(
      (const __attribute__((address_space(1))) void*)g,
      (__attribute__((address_space(3))) void*)l, 16, 0, 0);
}

__device__ __forceinline__ f32x4 mfma16(bf16x8 a, bf16x8 b, f32x4 c) {
  return __builtin_amdgcn_mfma_f32_16x16x32_bf16(a, b, c, 0, 0, 0);
}

__device__ __forceinline__ f32x16 mfma32(bf16x8 a, bf16x8 b, f32x16 c) {
  return __builtin_amdgcn_mfma_f32_32x32x16_bf16(a, b, c, 0, 0, 0);
}

// raw v_exp_f32 (skip libm range-fixup; |x| well within range here)
__device__ __forceinline__ float fexp2(float x) {
#if __has_builtin(__builtin_amdgcn_exp2f)
  return __builtin_amdgcn_exp2f(x);
#else
  float r; asm("v_exp_f32 %0, %1" : "=v"(r) : "v"(x)); return r;
#endif
}

// pack two f32 -> one u32 of 2 bf16 (lo = first arg)
__device__ __forceinline__ unsigned cvtpk(float lo, float hi) {
  unsigned r;
  asm("v_cvt_pk_bf16_f32 %0, %1, %2" : "=v"(r) : "v"(lo), "v"(hi));
  return r;
}

// ---------------- prep kernels ----------------

__global__ void cast_f32_bf16(const float* __restrict__ in, bf16* __restrict__ out, int n4) {
  int i = blockIdx.x * blockDim.x + threadIdx.x;
  if (i >= n4) return;
  float4 v = ((const float4*)in)[i];
  bf16x4 o;
  o[0] = (bf16)v.x; o[1] = (bf16)v.y; o[2] = (bf16)v.z; o[3] = (bf16)v.w;
  ((bf16x4*)out)[i] = o;
}

// in [R][C] fp32  ->  out [C][R] bf16
__global__ void tcast(const float* __restrict__ in, bf16* __restrict__ out, int R, int C) {
  __shared__ float t[32][33];
  int c0 = blockIdx.x * 32, r0 = blockIdx.y * 32;
  int tx = threadIdx.x, ty = threadIdx.y;
  #pragma unroll
  for (int i = 0; i < 4; i++)
    t[ty + i*8][tx] = in[(size_t)(r0 + ty + i*8) * C + c0 + tx];
  __syncthreads();
  #pragma unroll
  for (int i = 0; i < 4; i++)
    out[(size_t)(c0 + ty + i*8) * R + r0 + tx] = (bf16)t[tx][ty + i*8];
}

// ---------------- GEMM: C[M][N] = A[M][K](bf16) * Bt[N][K](bf16)^T ----------------
// BK=64, XOR-swizzled LDS (pre-swizzled global source + swizzled ds_read, rule 21).
// XCD-aware bijective block swizzle (nwg % 8 == 0 for both instantiations).
// EPI 0: scatter q/k head-major (q scaled by QSCALE) and v directly TRANSPOSED
//        into vt[BH][64][SEQ]; EPI 1: fp32 out = acc + x.

template <int EPI>
__global__ __launch_bounds__(256, 3) void gemm_bt(
    const bf16* __restrict__ A, const bf16* __restrict__ Bt, int K, int N,
    bf16* __restrict__ qb, bf16* __restrict__ kb, bf16* __restrict__ vtb,
    const float* __restrict__ xres, float* __restrict__ outf) {
  __shared__ alignas(16) bf16 As[128 * 64];
  __shared__ alignas(16) bf16 Bs[128 * 64];
  const int tid = threadIdx.x;
  const int wave = tid >> 6, lane = tid & 63;
  const int wr = wave >> 1, wc = wave & 1;

  // XCD swizzle: consecutive work-tiles land on the same XCD's L2
  const int nwg = gridDim.x * gridDim.y;
  const int id = blockIdx.y * gridDim.x + blockIdx.x;
  const int swz = (id & 7) * (nwg >> 3) + (id >> 3);
  const int bx = swz % gridDim.x, by = swz / gridDim.x;
  const int m0 = by * 128, n0 = bx * 128;

  const int srow = lane >> 3;                    // row within 8-row chunk
  const int scol = ((lane & 7) ^ srow) * 8;      // pre-swizzled source column
  const int lr16 = lane & 15, lg = lane >> 4;
  const int rsw = (lr16 & 7) << 4;
  const int cA = (lg * 16) ^ rsw;
  const int cB = (64 + lg * 16) ^ rsw;
  const char* aP = (const char*)As + (wr*64 + lr16) * 128;
  const char* bP = (const char*)Bs + (wc*64 + lr16) * 128;

  f32x4 acc[4][4];
  #pragma unroll
  for (int m = 0; m < 4; m++)
    #pragma unroll
    for (int n = 0; n < 4; n++) acc[m][n] = (f32x4)0.0f;

  for (int k0 = 0; k0 < K; k0 += 64) {
    #pragma unroll
    for (int j = 0; j < 4; j++) {
      const int c = wave * 4 + j;                // 8-row chunk index (0..15)
      gload16(A  + (size_t)(m0 + c*8 + srow) * K + k0 + scol, &As[c * 512]);
      gload16(Bt + (size_t)(n0 + c*8 + srow) * K + k0 + scol, &Bs[c * 512]);
    }
    __syncthreads();
    bf16x8 af[4][2], bfr[4][2];
    #pragma unroll
    for (int m = 0; m < 4; m++) {
      af[m][0] = *(const bf16x8*)(aP + m*2048 + cA);
      af[m][1] = *(const bf16x8*)(aP + m*2048 + cB);
    }
    #pragma unroll
    for (int n = 0; n < 4; n++) {
      bfr[n][0] = *(const bf16x8*)(bP + n*2048 + cA);
      bfr[n][1] = *(const bf16x8*)(bP + n*2048 + cB);
    }
    #pragma unroll
    for (int m = 0; m < 4; m++)
      #pragma unroll
      for (int n = 0; n < 4; n++) {
        acc[m][n] = mfma16(af[m][0], bfr[n][0], acc[m][n]);
        acc[m][n] = mfma16(af[m][1], bfr[n][1], acc[m][n]);
      }
    __syncthreads();
  }

  #pragma unroll
  for (int n = 0; n < 4; n++) {
    const int colg = n0 + wc*64 + n*16 + lr16;
    if (EPI == 0) {
      const int which = colg >> 10;           // 0=q 1=k 2=v
      const int win = colg & 1023;
      const int h = win >> 6, d = win & 63;
      #pragma unroll
      for (int m = 0; m < 4; m++) {
        const int rowg0 = m0 + wr*64 + m*16 + lg*4;
        #pragma unroll
        for (int j = 0; j < 4; j++) {
          const int rowg = rowg0 + j;
          const int b = rowg >> 11, r = rowg & 2047;
          const int bh = (b << 4) + h;
          if (which == 2) {
            // v -> transposed layout vt[bh][d][r]
            vtb[((size_t)bh * DHEAD + d) * SEQ + r] = (bf16)acc[m][n][j];
          } else {
            bf16* dst = (which == 0) ? qb : kb;
            const float sc = (which == 0) ? QSCALE : 1.0f;
            dst[((size_t)bh * SEQ + r) * DHEAD + d] = (bf16)(acc[m][n][j] * sc);
          }
        }
      }
    } else {
      #pragma unroll
      for (int m = 0; m < 4; m++) {
        const int rowg0 = m0 + wr*64 + m*16 + lg*4;
        #pragma unroll
        for (int j = 0; j < 4; j++) {
          const size_t idx = (size_t)(rowg0 + j) * N + colg;
          outf[idx] = acc[m][n][j] + xres[idx];
        }
      }
    }
  }
}

// ---------------- flash attention: 32x32x16 MFMA, in-block KV split ----------------
// R12 structure (57.7 us) + T15-style half-interleave: 512-thread block = 8 waves,
// wave w -> (q-subtile qw = w&3 [32 rows], kv-half kh2 = w>>2 [1024 kv]). K and V
// LDS-staged (double-buffered, swizzled) per kv-half. Per 64-kv tile: BOTH 32-kv
// QK^T clusters issue back-to-back (softmax-A's VALU work overlaps QK^T-B's MFMA
// execution; exp2-B overlaps PV-A), one combined defer-max vote, then
// {exp2,pack,PV} per half. P reg-resident via cvtpk + 2-shfl exchange. Partner
// kv-halves merge online-softmax partials via LDS at the end.
__global__ __launch_bounds__(512, 2) void attn_kernel(
    const bf16* __restrict__ q, const bf16* __restrict__ k,
    const bf16* __restrict__ vt, bf16* __restrict__ o) {
  // [kh2:32KB][buf:16KB][K/V:8KB] bf16 staging; merge area aliases after final barrier
  __shared__ alignas(16) char smraw[65536];
  bf16* kvb = (bf16*)smraw;
  float* mg = (float*)smraw;

  const int tid = threadIdx.x;
  const int wave = tid >> 6, lane = tid & 63;
  const int qw = wave & 3, kh2 = wave >> 2;
  const int l31 = lane & 31, hi = lane >> 5;
  const int bh = blockIdx.y;
  const int b = bh >> 4, h = bh & 15;
  const int qr = blockIdx.x * 128 + qw * 32;
  const bf16* kh = k  + (size_t)bh * SEQ * DHEAD;
  const bf16* vh = vt + (size_t)bh * DHEAD * SEQ;

  // staging: within a kv-half, wave qw covers rows [qw*16, qw*16+16) of the 64-row tile
  const int srow = lane >> 3;
  const int scol = ((lane & 7) ^ srow) * 8;
  const bf16* kg = kh + (size_t)(kh2 * 1024 + qw * 16 + srow) * DHEAD + scol;
  const bf16* vg = vh + (size_t)(qw * 16 + srow) * SEQ + kh2 * 1024 + scol;
  bf16* ldsK0 = kvb + kh2 * 16384 +        qw * 1024;
  bf16* ldsK1 = kvb + kh2 * 16384 + 8192 + qw * 1024;
  bf16* ldsV0 = kvb + kh2 * 16384 + 4096 +        qw * 1024;
  bf16* ldsV1 = kvb + kh2 * 16384 + 8192 + 4096 + qw * 1024;

  // Q fragments (B operand): lane holds q-row (qr+l31), k = ks*16 + hi*8 + j
  const bf16* qrow = q + (size_t)bh * SEQ * DHEAD + (size_t)(qr + l31) * DHEAD;
  bf16x8 qf[4];
  #pragma unroll
  for (int ks = 0; ks < 4; ks++)
    qf[ks] = *(const bf16x8*)&qrow[ks * 16 + hi * 8];

  float mr = 0.0f, lsum = 0.0f;
  f32x16 acc0 = (f32x16)0.0f, acc1 = (f32x16)0.0f;  // O^T d-tiles 0..31 / 32..63

  // hoisted read offsets: row = l31 (+32 for half 1), col slot XOR-swizzled by row&7
  const int rsw = (lane & 7) << 4;
  const int rowoff = l31 * 128;
  int cofs[4];
  #pragma unroll
  for (int ks = 0; ks < 4; ks++) cofs[ks] = (ks * 32 + hi * 16) ^ rsw;
  const char* kr0 = (const char*)(kvb + kh2 * 16384) + rowoff;
  const char* kr1 = (const char*)(kvb + kh2 * 16384 + 8192) + rowoff;
  const char* vr0 = (const char*)(kvb + kh2 * 16384 + 4096) + rowoff;
  const char* vr1 = (const char*)(kvb + kh2 * 16384 + 8192 + 4096) + rowoff;

  // prologue: stage tile 0 into buf 0
  gload16(kg, ldsK0); gload16(kg + 8 * DHEAD, ldsK0 + 512);
  gload16(vg, ldsV0); gload16(vg + 8 * SEQ,   ldsV0 + 512);
  kg += 64 * DHEAD; vg += 64;
  __syncthreads();

  const int NT = 1024 / 64;   // 16 iters per kv-half
  for (int t = 0; t < NT; ++t) {
    // stage next tile into the other buffer (wave-uniform selects, no arrays)
    bf16* dK = (t & 1) ? ldsK0 : ldsK1;
    bf16* dV = (t & 1) ? ldsV0 : ldsV1;
    if (t + 1 < NT) {
      gload16(kg, dK); gload16(kg + 8 * DHEAD, dK + 512);
      gload16(vg, dV); gload16(vg + 8 * SEQ,   dV + 512);
      kg += 64 * DHEAD; vg += 64;
    }
    const char* kr = (t & 1) ? kr1 : kr0;
    const char* vr = (t & 1) ? vr1 : vr0;

    // ---- QK^T for BOTH 32-kv halves, back-to-back MFMA clusters
    const float nmr = -mr;
    f32x16 sA = (f32x16)nmr, sB = (f32x16)nmr;
    __builtin_amdgcn_s_setprio(1);
    #pragma unroll
    for (int ks = 0; ks < 4; ks++) {
      bf16x8 kf = *(const bf16x8*)(kr + cofs[ks]);
      sA = mfma32(kf, qf[ks], sA);
    }
    #pragma unroll
    for (int ks = 0; ks < 4; ks++) {
      bf16x8 kf = *(const bf16x8*)(kr + 4096 + cofs[ks]);
      sB = mfma32(kf, qf[ks], sB);
    }
    __builtin_amdgcn_s_setprio(0);

    // ---- combined defer-max over both halves (one vote per 64 kv)
    {
      const float a0 = fmaxf(fmaxf(sA[0], sA[1]), fmaxf(sA[2], sA[3]));
      const float a1 = fmaxf(fmaxf(sA[4], sA[5]), fmaxf(sA[6], sA[7]));
      const float a2 = fmaxf(fmaxf(sA[8], sA[9]), fmaxf(sA[10], sA[11]));
      const float a3 = fmaxf(fmaxf(sA[12], sA[13]), fmaxf(sA[14], sA[15]));
      const float b0 = fmaxf(fmaxf(sB[0], sB[1]), fmaxf(sB[2], sB[3]));
      const float b1 = fmaxf(fmaxf(sB[4], sB[5]), fmaxf(sB[6], sB[7]));
      const float b2 = fmaxf(fmaxf(sB[8], sB[9]), fmaxf(sB[10], sB[11]));
      const float b3 = fmaxf(fmaxf(sB[12], sB[13]), fmaxf(sB[14], sB[15]));
      const float lmax = fmaxf(fmaxf(fmaxf(a0, a1), fmaxf(a2, a3)),
                               fmaxf(fmaxf(b0, b1), fmaxf(b2, b3)));
      if (!__all(lmax <= DEFER_THR)) {       // rare: rescale both halves
        float mx = fmaxf(lmax, __shfl_xor(lmax, 32));
        mx = fmaxf(mx, 0.0f);
        const float corr = fexp2(-mx);
        lsum *= corr;
        acc0 *= corr; acc1 *= corr;
        mr += mx;
        #pragma unroll
        for (int r = 0; r < 16; r++) { sA[r] -= mx; sB[r] -= mx; }
      }
    }

    // ---- half A: exp2 + sum + pack + PV (exp2-B / PV-A overlap via issue order)
    #pragma unroll
    for (int r = 0; r < 16; r++) sA[r] = fexp2(sA[r]);
    lsum += (((sA[0] + sA[1]) + (sA[2] + sA[3])) + ((sA[4] + sA[5]) + (sA[6] + sA[7])))
          + (((sA[8] + sA[9]) + (sA[10] + sA[11])) + ((sA[12] + sA[13]) + (sA[14] + sA[15])));
    __builtin_amdgcn_s_setprio(1);
    #pragma unroll
    for (int u = 0; u < 2; ++u) {
      const unsigned w0 = cvtpk(sA[8*u + 0], sA[8*u + 1]);
      const unsigned w1 = cvtpk(sA[8*u + 2], sA[8*u + 3]);
      const unsigned w2 = cvtpk(sA[8*u + 4], sA[8*u + 5]);
      const unsigned w3 = cvtpk(sA[8*u + 6], sA[8*u + 7]);
      const unsigned t0 = hi ? w0 : w2;
      const unsigned t1 = hi ? w1 : w3;
      const unsigned r0 = (unsigned)__shfl_xor((int)t0, 32);
      const unsigned r1 = (unsigned)__shfl_xor((int)t1, 32);
      u32x4 fw;
      fw[0] = hi ? r0 : w0;
      fw[1] = hi ? r1 : w1;
      fw[2] = hi ? w2 : r0;
      fw[3] = hi ? w3 : r1;
      bf16x8 pf = __builtin_bit_cast(bf16x8, fw);
      bf16x8 vf0 = *(const bf16x8*)(vr + cofs[u]);
      bf16x8 vf1 = *(const bf16x8*)(vr + 4096 + cofs[u]);
      acc0 = mfma32(vf0, pf, acc0);
      acc1 = mfma32(vf1, pf, acc1);
    }
    __builtin_amdgcn_s_setprio(0);

    // ---- half B: exp2 + sum + pack + PV
    #pragma unroll
    for (int r = 0; r < 16; r++) sB[r] = fexp2(sB[r]);
    lsum += (((sB[0] + sB[1]) + (sB[2] + sB[3])) + ((sB[4] + sB[5]) + (sB[6] + sB[7])))
          + (((sB[8] + sB[9]) + (sB[10] + sB[11])) + ((sB[12] + sB[13]) + (sB[14] + sB[15])));
    __builtin_amdgcn_s_setprio(1);
    #pragma unroll
    for (int u = 0; u < 2; ++u) {
      const unsigned w0 = cvtpk(sB[8*u + 0], sB[8*u + 1]);
      const unsigned w1 = cvtpk(sB[8*u + 2], sB[8*u + 3]);
      const unsigned w2 = cvtpk(sB[8*u + 4], sB[8*u + 5]);
      const unsigned w3 = cvtpk(sB[8*u + 6], sB[8*u + 7]);
      const unsigned t0 = hi ? w0 : w2;
      const unsigned t1 = hi ? w1 : w3;
      const unsigned r0 = (unsigned)__shfl_xor((int)t0, 32);
      const unsigned r1 = (unsigned)__shfl_xor((int)t1, 32);
      u32x4 fw;
      fw[0] = hi ? r0 : w0;
      fw[1] = hi ? r1 : w1;
      fw[2] = hi ? w2 : r0;
      fw[3] = hi ? w3 : r1;
      bf16x8 pf = __builtin_bit_cast(bf16x8, fw);
      const int ksl = 2 + u;
      bf16x8 vf0 = *(const bf16x8*)(vr + cofs[ksl]);
      bf16x8 vf1 = *(const bf16x8*)(vr + 4096 + cofs[ksl]);
      acc0 = mfma32(vf0, pf, acc0);
      acc1 = mfma32(vf1, pf, acc1);
    }
    __builtin_amdgcn_s_setprio(0);

    __syncthreads();   // drains vmcnt (staging) + lgkm; flips buffers safely
  }

  // ---- cross-wave merge of the two kv-halves (exact online-softmax merge) ----
  // First merge lsum across the lane pair (l, l+32) sharing this q row.
  lsum += __shfl_xor(lsum, 32);

  if (kh2 == 1) {
    // upper waves publish partials: 16+16 acc + lsum + mr, stride 35 f32 (bank-clean)
    float* dst = &mg[(qw * 64 + lane) * 35];
    #pragma unroll
    for (int r = 0; r < 16; r++) dst[r] = acc0[r];
    #pragma unroll
    for (int r = 0; r < 16; r++) dst[16 + r] = acc1[r];
    dst[32] = lsum; dst[33] = mr;
  }
  __syncthreads();
  if (kh2 == 0) {
    const float* src = &mg[(qw * 64 + lane) * 35];
    const float lsb = src[32], mrb = src[33];
    const float M  = fmaxf(mr, mrb);
    const float wa = fexp2(mr - M), wb = fexp2(mrb - M);
    const float inv = 1.0f / (lsum * wa + lsb * wb);
    const float fa = wa * inv, fb = wb * inv;

    bf16* orow = o + ((size_t)(b * SEQ + qr + l31)) * D_MODEL + h * 64 + hi * 4;
    #pragma unroll
    for (int g = 0; g < 4; g++) {
      bf16x4 o0, o1;
      #pragma unroll
      for (int e = 0; e < 4; e++) {
        o0[e] = (bf16)(acc0[4*g + e] * fa + src[4*g + e] * fb);
        o1[e] = (bf16)(acc1[4*g + e] * fa + src[16 + 4*g + e] * fb);
      }
      *(bf16x4*)&orow[8 * g]      = o0;   // d = 8g + 4hi + e
      *(bf16x4*)&orow[32 + 8 * g] = o1;   // d = 32 + 8g + 4hi + e
    }
  }
}

// ---------------- launch ----------------

extern "C" void kernel_launch(void* const* d_in, const int* in_sizes, int n_in,
                              void* d_out, int out_size, void* d_ws, size_t ws_size,
                              hipStream_t stream) {
  const float* x      = (const float*)d_in[0];
  const float* w_qkv  = (const float*)d_in[1];
  const float* w_proj = (const float*)d_in[2];
  float* outf = (float*)d_out;

  bf16* xb    = (bf16*)d_ws;                                 // 4096*1024
  bf16* wqkvT = xb    + (size_t)MROWS * D_MODEL;             // 3072*1024
  bf16* wpT   = wqkvT + (size_t)3 * D_MODEL * D_MODEL;       // 1024*1024
  bf16* qb    = wpT   + (size_t)D_MODEL * D_MODEL;           // 32*2048*64
  bf16* kb    = qb    + (size_t)BHTOT * SEQ * DHEAD;
  bf16* vtb   = kb    + (size_t)BHTOT * SEQ * DHEAD;         // [BH][64][SEQ]
  bf16* ob    = xb;   // alias: xb dead after GEMM1

  dim3 tb(32, 8);

  cast_f32_bf16<<<(MROWS * D_MODEL / 4 + 255) / 256, 256, 0, stream>>>(
      x, xb, MROWS * D_MODEL / 4);
  tcast<<<dim3(3 * D_MODEL / 32, D_MODEL / 32), tb, 0, stream>>>(
      w_qkv, wqkvT, D_MODEL, 3 * D_MODEL);
  tcast<<<dim3(D_MODEL / 32, D_MODEL / 32), tb, 0, stream>>>(
      w_proj, wpT, D_MODEL, D_MODEL);

  gemm_bt<0><<<dim3(3 * D_MODEL / 128, MROWS / 128), 256, 0, stream>>>(
      xb, wqkvT, D_MODEL, 3 * D_MODEL, qb, kb, vtb, nullptr, nullptr);

  attn_kernel<<<dim3(SEQ / 128, BHTOT), 512, 0, stream>>>(qb, kb, vtb, ob);

  gemm_bt<1><<<dim3(D_MODEL / 128, MROWS / 128), 256, 0, stream>>>(
      ob, wpT, D_MODEL, D_MODEL, nullptr, nullptr, nullptr, x, outf);
}